// Round 1
// baseline (1793.122 us; speedup 1.0000x reference)
//
#include <hip/hip_runtime.h>

typedef float floatx4_t __attribute__((ext_vector_type(4)));
typedef __bf16 bf16x8_t __attribute__((ext_vector_type(8)));
typedef short shortx8_t __attribute__((ext_vector_type(8)));

__device__ __forceinline__ unsigned short f2bf_rne(float f) {
    unsigned u = __float_as_uint(f);
    unsigned r = u + 0x7FFFu + ((u >> 16) & 1u);
    return (unsigned short)(r >> 16);
}

// ---------------- degree (weighted, by col) ----------------
__global__ __launch_bounds__(256) void k_deg(const int* __restrict__ col,
                                             const float* __restrict__ w,
                                             float* __restrict__ deg, int E) {
    int e = blockIdx.x * 256 + threadIdx.x;
    if (e < E) unsafeAtomicAdd(&deg[col[e]], w[e]);
}

// ---------------- deg -> deg^{-1/2} in place ----------------
__global__ __launch_bounds__(256) void k_dis(float* __restrict__ deg, int N) {
    int n = blockIdx.x * 256 + threadIdx.x;
    if (n < N) {
        float d = deg[n];
        deg[n] = (d > 0.f) ? rsqrtf(d) : 0.f;
    }
}

// ---------------- norm[e] = dis[row]*w*dis[col] ----------------
__global__ __launch_bounds__(256) void k_norm(const int* __restrict__ row,
                                              const int* __restrict__ col,
                                              const float* __restrict__ w,
                                              const float* __restrict__ dis,
                                              float* __restrict__ nrm, int E) {
    int e = blockIdx.x * 256 + threadIdx.x;
    if (e < E) nrm[e] = dis[row[e]] * w[e] * dis[col[e]];
}

// ---------------- h1 = x @ W1  (N x 512 @ 512 x 16), bf16 MFMA ----------------
// wave handles 16 nodes; block = 4 waves = 64 nodes
__global__ __launch_bounds__(256) void k_gemm1(const float* __restrict__ x,
                                               const float* __restrict__ W1,
                                               float* __restrict__ h1, int N) {
    const int lane = threadIdx.x & 63;
    const int wave = threadIdx.x >> 6;
    const int m = lane & 15;   // node-within-tile for A; f-column for B
    const int q = lane >> 4;   // quad -> k slice
    const int base = blockIdx.x * 64 + wave * 16;

    // B fragments: lane holds W1[k][m] for k = c*32 + q*8 + j  (held in 64 VGPRs)
    shortx8_t bs[16];
#pragma unroll
    for (int c = 0; c < 16; ++c) {
#pragma unroll
        for (int j = 0; j < 8; ++j) {
            int k = c * 32 + q * 8 + j;
            bs[c][j] = (short)f2bf_rne(W1[k * 16 + m]);
        }
    }

    int row = base + m;
    if (row >= N) row = N - 1;  // clamp for tail; stores are guarded
    const float* xr = x + (size_t)row * 512;

    floatx4_t acc = {0.f, 0.f, 0.f, 0.f};
#pragma unroll
    for (int c = 0; c < 16; ++c) {
        const float4 u0 = *(const float4*)(xr + c * 32 + q * 8);
        const float4 u1 = *(const float4*)(xr + c * 32 + q * 8 + 4);
        shortx8_t as;
        as[0] = (short)f2bf_rne(u0.x); as[1] = (short)f2bf_rne(u0.y);
        as[2] = (short)f2bf_rne(u0.z); as[3] = (short)f2bf_rne(u0.w);
        as[4] = (short)f2bf_rne(u1.x); as[5] = (short)f2bf_rne(u1.y);
        as[6] = (short)f2bf_rne(u1.z); as[7] = (short)f2bf_rne(u1.w);
        acc = __builtin_amdgcn_mfma_f32_16x16x32_bf16(
            __builtin_bit_cast(bf16x8_t, as),
            __builtin_bit_cast(bf16x8_t, bs[c]), acc, 0, 0, 0);
    }

    // D: lane holds D[row = q*4 + r][col = m]
#pragma unroll
    for (int r = 0; r < 4; ++r) {
        int node = base + q * 4 + r;
        if (node < N) h1[(size_t)node * 16 + m] = acc[r];
    }
}

// ---------------- edge aggregation: dst[col] += norm * src[row], 16-wide ----------------
// 4 threads per edge, one float4 quarter each
__global__ __launch_bounds__(256) void k_agg(const int* __restrict__ row,
                                             const int* __restrict__ col,
                                             const float* __restrict__ nrm,
                                             const float* __restrict__ src,
                                             float* __restrict__ dst, int E) {
    int t = blockIdx.x * 256 + threadIdx.x;
    int e = t >> 2, qq = t & 3;
    if (e >= E) return;
    int r = row[e], c = col[e];
    float nm = nrm[e];
    const float4 hv = *(const float4*)(src + (size_t)r * 16 + qq * 4);
    float* d = dst + (size_t)c * 16 + qq * 4;
    unsafeAtomicAdd(d + 0, nm * hv.x);
    unsafeAtomicAdd(d + 1, nm * hv.y);
    unsafeAtomicAdd(d + 2, nm * hv.z);
    unsafeAtomicAdd(d + 3, nm * hv.w);
}

// ---------------- h = relu(agg1 + b1), in place ----------------
__global__ __launch_bounds__(256) void k_relu_bias(float* __restrict__ a,
                                                   const float* __restrict__ b1,
                                                   int total) {
    int i = blockIdx.x * 256 + threadIdx.x;
    if (i < total) {
        float v = a[i] + b1[i & 15];
        a[i] = v > 0.f ? v : 0.f;
    }
}

// ---------------- out = log_softmax(agg2 @ W2 + b2) ----------------
__global__ __launch_bounds__(256) void k_out(const float* __restrict__ agg2,
                                             const float* __restrict__ W2,
                                             const float* __restrict__ b2,
                                             float* __restrict__ out, int N) {
    __shared__ float w2s[16 * 40];
    __shared__ float b2s[40];
    int t = threadIdx.x;
    for (int i = t; i < 640; i += 256) w2s[i] = W2[i];
    if (t < 40) b2s[t] = b2[t];
    __syncthreads();

    int n = blockIdx.x * 256 + t;
    if (n >= N) return;

    float a[16];
    const float* ar = agg2 + (size_t)n * 16;
#pragma unroll
    for (int f = 0; f < 16; ++f) a[f] = ar[f];

    float z[40];
#pragma unroll
    for (int c = 0; c < 40; ++c) z[c] = b2s[c];
#pragma unroll
    for (int f = 0; f < 16; ++f) {
        float af = a[f];
#pragma unroll
        for (int c = 0; c < 40; ++c) z[c] += af * w2s[f * 40 + c];
    }

    float mx = z[0];
#pragma unroll
    for (int c = 1; c < 40; ++c) mx = fmaxf(mx, z[c]);
    float s = 0.f;
#pragma unroll
    for (int c = 0; c < 40; ++c) s += __expf(z[c] - mx);
    float lse = mx + __logf(s);

    float* orow = out + (size_t)n * 40;
#pragma unroll
    for (int c = 0; c < 10; ++c) {
        float4 v = make_float4(z[c * 4 + 0] - lse, z[c * 4 + 1] - lse,
                               z[c * 4 + 2] - lse, z[c * 4 + 3] - lse);
        *(float4*)(orow + c * 4) = v;
    }
}

extern "C" void kernel_launch(void* const* d_in, const int* in_sizes, int n_in,
                              void* d_out, int out_size, void* d_ws, size_t ws_size,
                              hipStream_t stream) {
    const float* x  = (const float*)d_in[0];
    const int*   ei = (const int*)d_in[1];
    const float* ew = (const float*)d_in[2];
    const float* W1 = (const float*)d_in[3];
    const float* b1 = (const float*)d_in[4];
    const float* W2 = (const float*)d_in[5];
    const float* b2 = (const float*)d_in[6];

    const int N = in_sizes[0] / 512;
    const int E = in_sizes[2];
    const int* row = ei;       // edge_index[0]
    const int* col = ei + E;   // edge_index[1]

    float* ws   = (float*)d_ws;
    float* deg  = ws;                         // N floats (becomes dis in place)
    float* agg1 = ws + N;                     // 16N (becomes h in place)
    float* agg2 = ws + (size_t)17 * N;        // 16N
    float* nrm  = ws + (size_t)33 * N;        // E
    float* h1   = nrm + E;                    // 16N
    // total: (49N + E)*4 bytes ~= 32.4 MB

    // zero deg + agg1 + agg2 (contiguous first 33N floats)
    hipMemsetAsync(deg, 0, (size_t)33 * N * sizeof(float), stream);

    const int gE  = (E + 255) / 256;
    const int gN  = (N + 255) / 256;
    const int gE4 = (E * 4 + 255) / 256;

    k_deg<<<gE, 256, 0, stream>>>(col, ew, deg, E);
    k_dis<<<gN, 256, 0, stream>>>(deg, N);
    k_norm<<<gE, 256, 0, stream>>>(row, col, ew, deg, nrm, E);
    k_gemm1<<<(N + 63) / 64, 256, 0, stream>>>(x, W1, h1, N);
    k_agg<<<gE4, 256, 0, stream>>>(row, col, nrm, h1, agg1, E);
    k_relu_bias<<<(16 * N + 255) / 256, 256, 0, stream>>>(agg1, b1, 16 * N);
    k_agg<<<gE4, 256, 0, stream>>>(row, col, nrm, agg1, agg2, E);
    k_out<<<gN, 256, 0, stream>>>(agg2, W2, b2, (float*)d_out, N);
}

// Round 2
// 858.036 us; speedup vs baseline: 2.0898x; 2.0898x over previous
//
#include <hip/hip_runtime.h>

typedef float floatx4_t __attribute__((ext_vector_type(4)));
typedef __bf16 bf16x8_t __attribute__((ext_vector_type(8)));
typedef short shortx8_t __attribute__((ext_vector_type(8)));

__device__ __forceinline__ unsigned short f2bf_rne(float f) {
    unsigned u = __float_as_uint(f);
    unsigned r = u + 0x7FFFu + ((u >> 16) & 1u);
    return (unsigned short)(r >> 16);
}

// ---------------- histogram of col ----------------
__global__ __launch_bounds__(256) void k_hist(const int* __restrict__ col,
                                              int* __restrict__ cnt, int E) {
    int e = blockIdx.x * 256 + threadIdx.x;
    if (e < E) atomicAdd(&cnt[col[e]], 1);
}

// ---------------- scan pass 1: per-block sums of 1024 ----------------
__global__ __launch_bounds__(256) void k_scan1(const int* __restrict__ cnt,
                                               int* __restrict__ bsums, int N) {
    __shared__ int lds[256];
    int t = threadIdx.x;
    int base = blockIdx.x * 1024 + t * 4;
    int s = 0;
#pragma unroll
    for (int j = 0; j < 4; ++j) s += (base + j < N) ? cnt[base + j] : 0;
    lds[t] = s;
    __syncthreads();
    for (int off = 128; off > 0; off >>= 1) {
        if (t < off) lds[t] += lds[t + off];
        __syncthreads();
    }
    if (t == 0) bsums[blockIdx.x] = lds[0];
}

// ---------------- scan pass 2: exclusive scan of block sums (nb <= 256) ----------------
__global__ __launch_bounds__(256) void k_scan2(int* __restrict__ bsums, int nb) {
    __shared__ int lds[256];
    int t = threadIdx.x;
    int v = (t < nb) ? bsums[t] : 0;
    lds[t] = v;
    __syncthreads();
    for (int off = 1; off < 256; off <<= 1) {
        int x = (t >= off) ? lds[t - off] : 0;
        __syncthreads();
        lds[t] += x;
        __syncthreads();
    }
    if (t < nb) bsums[t] = lds[t] - v;  // exclusive
}

// ---------------- scan pass 3: full exclusive scan -> rowptr + cursor ----------------
__global__ __launch_bounds__(256) void k_scan3(const int* __restrict__ cnt,
                                               const int* __restrict__ bsums,
                                               int* __restrict__ rowptr,
                                               int* __restrict__ cursor,
                                               int N, int E) {
    __shared__ int lds[256];
    int t = threadIdx.x;
    int base = blockIdx.x * 1024 + t * 4;
    int v[4];
    int s = 0;
#pragma unroll
    for (int j = 0; j < 4; ++j) {
        v[j] = (base + j < N) ? cnt[base + j] : 0;
        s += v[j];
    }
    lds[t] = s;
    __syncthreads();
    for (int off = 1; off < 256; off <<= 1) {
        int x = (t >= off) ? lds[t - off] : 0;
        __syncthreads();
        lds[t] += x;
        __syncthreads();
    }
    int run = lds[t] - s + bsums[blockIdx.x];
#pragma unroll
    for (int j = 0; j < 4; ++j) {
        if (base + j < N) {
            rowptr[base + j] = run;
            cursor[base + j] = run;
            run += v[j];
        }
    }
    if (blockIdx.x == 0 && t == 0) rowptr[N] = E;
}

// ---------------- scatter into CSR order ----------------
__global__ __launch_bounds__(256) void k_scatter(const int* __restrict__ row,
                                                 const int* __restrict__ col,
                                                 const float* __restrict__ ew,
                                                 int* __restrict__ cursor,
                                                 int* __restrict__ rowp,
                                                 float* __restrict__ ewp, int E) {
    int e = blockIdx.x * 256 + threadIdx.x;
    if (e >= E) return;
    int c = col[e];
    int pos = atomicAdd(&cursor[c], 1);
    rowp[pos] = row[e];
    ewp[pos] = ew[e];
}

// ---------------- dis[n] = rsqrt(sum ewp over bucket) ----------------
__global__ __launch_bounds__(256) void k_degdis(const int* __restrict__ rowptr,
                                                const float* __restrict__ ewp,
                                                float* __restrict__ dis, int N) {
    int n = blockIdx.x * 256 + threadIdx.x;
    if (n >= N) return;
    int beg = rowptr[n], end = rowptr[n + 1];
    float s = 0.f;
    for (int i = beg; i < end; ++i) s += ewp[i];
    dis[n] = (s > 0.f) ? rsqrtf(s) : 0.f;
}

// ---------------- h1 = x @ W1  (N x 512 @ 512 x 16), bf16 MFMA ----------------
__global__ __launch_bounds__(256) void k_gemm1(const float* __restrict__ x,
                                               const float* __restrict__ W1,
                                               float* __restrict__ h1, int N) {
    const int lane = threadIdx.x & 63;
    const int wave = threadIdx.x >> 6;
    const int m = lane & 15;
    const int q = lane >> 4;
    const int base = blockIdx.x * 64 + wave * 16;

    shortx8_t bs[16];
#pragma unroll
    for (int c = 0; c < 16; ++c) {
#pragma unroll
        for (int j = 0; j < 8; ++j) {
            int k = c * 32 + q * 8 + j;
            bs[c][j] = (short)f2bf_rne(W1[k * 16 + m]);
        }
    }

    int row = base + m;
    if (row >= N) row = N - 1;
    const float* xr = x + (size_t)row * 512;

    floatx4_t acc = {0.f, 0.f, 0.f, 0.f};
#pragma unroll
    for (int c = 0; c < 16; ++c) {
        const float4 u0 = *(const float4*)(xr + c * 32 + q * 8);
        const float4 u1 = *(const float4*)(xr + c * 32 + q * 8 + 4);
        shortx8_t as;
        as[0] = (short)f2bf_rne(u0.x); as[1] = (short)f2bf_rne(u0.y);
        as[2] = (short)f2bf_rne(u0.z); as[3] = (short)f2bf_rne(u0.w);
        as[4] = (short)f2bf_rne(u1.x); as[5] = (short)f2bf_rne(u1.y);
        as[6] = (short)f2bf_rne(u1.z); as[7] = (short)f2bf_rne(u1.w);
        acc = __builtin_amdgcn_mfma_f32_16x16x32_bf16(
            __builtin_bit_cast(bf16x8_t, as),
            __builtin_bit_cast(bf16x8_t, bs[c]), acc, 0, 0, 0);
    }

#pragma unroll
    for (int r = 0; r < 4; ++r) {
        int node = base + q * 4 + r;
        if (node < N) h1[(size_t)node * 16 + m] = acc[r];
    }
}

// ---------------- agg1: h[n] = relu(sum_e nrm*h1[rowp] + b1), gather ----------------
// 16 lanes per node, 16 nodes per block
__global__ __launch_bounds__(256) void k_agg1(const int* __restrict__ rowptr,
                                              const int* __restrict__ rowp,
                                              const float* __restrict__ ewp,
                                              const float* __restrict__ dis,
                                              const float* __restrict__ h1,
                                              const float* __restrict__ b1,
                                              float* __restrict__ h, int N) {
    int g = blockIdx.x * 16 + (threadIdx.x >> 4);
    int f = threadIdx.x & 15;
    if (g >= N) return;
    float disg = dis[g];
    int beg = rowptr[g], end = rowptr[g + 1];
    float acc = 0.f;
    for (int i = beg; i < end; ++i) {
        int r = rowp[i];
        float nm = dis[r] * ewp[i] * disg;
        acc += nm * h1[(size_t)r * 16 + f];
    }
    float v = acc + b1[f];
    h[(size_t)g * 16 + f] = v > 0.f ? v : 0.f;
}

// ---------------- agg2: agg2[n] = sum_e nrm*h[rowp], gather ----------------
__global__ __launch_bounds__(256) void k_agg2(const int* __restrict__ rowptr,
                                              const int* __restrict__ rowp,
                                              const float* __restrict__ ewp,
                                              const float* __restrict__ dis,
                                              const float* __restrict__ h,
                                              float* __restrict__ agg2, int N) {
    int g = blockIdx.x * 16 + (threadIdx.x >> 4);
    int f = threadIdx.x & 15;
    if (g >= N) return;
    float disg = dis[g];
    int beg = rowptr[g], end = rowptr[g + 1];
    float acc = 0.f;
    for (int i = beg; i < end; ++i) {
        int r = rowp[i];
        acc += dis[r] * ewp[i] * disg * h[(size_t)r * 16 + f];
    }
    agg2[(size_t)g * 16 + f] = acc;
}

// ---------------- out = log_softmax(agg2 @ W2 + b2) ----------------
__global__ __launch_bounds__(256) void k_out(const float* __restrict__ agg2,
                                             const float* __restrict__ W2,
                                             const float* __restrict__ b2,
                                             float* __restrict__ out, int N) {
    __shared__ float w2s[16 * 40];
    __shared__ float b2s[40];
    int t = threadIdx.x;
    for (int i = t; i < 640; i += 256) w2s[i] = W2[i];
    if (t < 40) b2s[t] = b2[t];
    __syncthreads();

    int n = blockIdx.x * 256 + t;
    if (n >= N) return;

    float a[16];
    const float* ar = agg2 + (size_t)n * 16;
#pragma unroll
    for (int f = 0; f < 16; ++f) a[f] = ar[f];

    float z[40];
#pragma unroll
    for (int c = 0; c < 40; ++c) z[c] = b2s[c];
#pragma unroll
    for (int f = 0; f < 16; ++f) {
        float af = a[f];
#pragma unroll
        for (int c = 0; c < 40; ++c) z[c] += af * w2s[f * 40 + c];
    }

    float mx = z[0];
#pragma unroll
    for (int c = 1; c < 40; ++c) mx = fmaxf(mx, z[c]);
    float s = 0.f;
#pragma unroll
    for (int c = 0; c < 40; ++c) s += __expf(z[c] - mx);
    float lse = mx + __logf(s);

    float* orow = out + (size_t)n * 40;
#pragma unroll
    for (int c = 0; c < 10; ++c) {
        float4 v = make_float4(z[c * 4 + 0] - lse, z[c * 4 + 1] - lse,
                               z[c * 4 + 2] - lse, z[c * 4 + 3] - lse);
        *(float4*)(orow + c * 4) = v;
    }
}

extern "C" void kernel_launch(void* const* d_in, const int* in_sizes, int n_in,
                              void* d_out, int out_size, void* d_ws, size_t ws_size,
                              hipStream_t stream) {
    const float* x  = (const float*)d_in[0];
    const int*   ei = (const int*)d_in[1];
    const float* ew = (const float*)d_in[2];
    const float* W1 = (const float*)d_in[3];
    const float* b1 = (const float*)d_in[4];
    const float* W2 = (const float*)d_in[5];
    const float* b2 = (const float*)d_in[6];

    const int N = in_sizes[0] / 512;
    const int E = in_sizes[2];
    const int* row = ei;
    const int* col = ei + E;

    // workspace layout (all 4-byte elems): ~40.1 MB
    int*   cnt    = (int*)d_ws;            // N
    int*   rowptr = cnt + N;               // N+1
    int*   cursor = rowptr + (N + 1);      // N
    int*   bsums  = cursor + N;            // 512
    int*   rowp   = bsums + 512;           // E
    float* ewp    = (float*)(rowp + E);    // E
    float* dis    = ewp + E;               // N
    float* h1     = dis + N;               // 16N (reused as agg2)
    float* h      = h1 + (size_t)16 * N;   // 16N
    float* agg2   = h1;                    // alias: h1 dead after k_agg1

    hipMemsetAsync(cnt, 0, (size_t)N * sizeof(int), stream);

    const int gE  = (E + 255) / 256;
    const int gN  = (N + 255) / 256;
    const int nb  = (N + 1023) / 1024;
    const int gG  = (N + 15) / 16;

    k_gemm1<<<(N + 63) / 64, 256, 0, stream>>>(x, W1, h1, N);
    k_hist<<<gE, 256, 0, stream>>>(col, cnt, E);
    k_scan1<<<nb, 256, 0, stream>>>(cnt, bsums, N);
    k_scan2<<<1, 256, 0, stream>>>(bsums, nb);
    k_scan3<<<nb, 256, 0, stream>>>(cnt, bsums, rowptr, cursor, N, E);
    k_scatter<<<gE, 256, 0, stream>>>(row, col, ew, cursor, rowp, ewp, E);
    k_degdis<<<gN, 256, 0, stream>>>(rowptr, ewp, dis, N);
    k_agg1<<<gG, 256, 0, stream>>>(rowptr, rowp, ewp, dis, h1, b1, h, N);
    k_agg2<<<gG, 256, 0, stream>>>(rowptr, rowp, ewp, dis, h, agg2, N);
    k_out<<<gN, 256, 0, stream>>>(agg2, W2, b2, (float*)d_out, N);
}